// Round 2
// 8693.728 us; speedup vs baseline: 1.1620x; 1.1620x over previous
//
#include <hip/hip_runtime.h>
#include <math.h>

// ---------------------------------------------------------------------------
// NCPDecoder: 3-cell CfC RNN, B=1024, T=256.
// Round 4->5 (retry; previous submit died to container-acquire failure, no
// kernel signal): cross-cell software pipelining + 2-col register blocking.
// R4 (10.1 ms): VALUBusy 63%, HBM 0.16%, L2 weight stream at 40% of ceiling
// -> issue/latency bound. Cells were serial per step (273 k4 critical path,
// 8 barriers); inner loop only 16 FMA per 4 LDS broadcasts.
// R5: c0@t / c1@t-1 / c2@t-2 computed in ONE matvec phase on disjoint wave
// groups (c0: waves 0-6, c1: 7-11, c2: 12-13, fc head: 14-15), combines in a
// second phase -> 2 barriers/phase, 259 phases. Each matvec thread owns TWO
// columns (32 FMA per 4 ds_read_b128) with ping-pong 4-row weight prefetch
// (no rotation movs, ~2 FMA-bodies between L2 load and use).
// Numerics per column are bit-identical to R4 (same k order, bias init).
// ---------------------------------------------------------------------------

namespace {
constexpr int kBatch = 1024;
constexpr int kT     = 256;
constexpr int kDIN   = 128;
constexpr int kUNITS = 512;
constexpr int kINTER = 269;
constexpr int kCMD   = 179;
constexpr int kMOTOR = 64;
constexpr int kOUT   = 64;

constexpr int kCAT0 = kDIN + kINTER;    // 397
constexpr int kCAT1 = kINTER + kCMD;    // 448
constexpr int kCAT2 = kCMD + kMOTOR;    // 243

// real combined col counts (ff1 | ff2 | ta+tb)
constexpr int kC0r = 3 * kINTER;  // 807
constexpr int kC1r = 3 * kCMD;    // 537
constexpr int kC2r = 3 * kMOTOR;  // 192
// padded col counts (even -> exact 2-col pairs; pad col is all-zero W, 0 bias)
constexpr int kC0p = 808;
constexpr int kC1p = 538;
constexpr int kC2p = 192;
// col pairs per cell (thread i owns cols i and i+kPx)
constexpr int kP0 = 404;
constexpr int kP1 = 269;
constexpr int kP2 = 96;
// k4 depths padded to multiples of 4 (ping-pong unroll) ; LDS a-strides
constexpr int kK40 = 100;               // 397 -> 400
constexpr int kK41 = 112;               // 448 exact
constexpr int kK42 = 64;                // 243 -> 256
constexpr int kS0 = kK40 * 4;           // 400
constexpr int kS1 = kK41 * 4;           // 448
constexpr int kS2 = kK42 * 4;           // 256

constexpr int kQ0 = kK40 * kC0p;        // 80800 float4 quads
constexpr int kQ1 = kK41 * kC1p;        // 60256
constexpr int kQ2 = kK42 * kC2p;        // 12288
constexpr int kQ  = kQ0 + kQ1 + kQ2;    // 153344
constexpr int kBCN = kC0p + kC1p + kC2p;  // 1538 fused biases (padded coords)
constexpr int kBCOff = kQ * 4;          // float offset of biases in ws

constexpr int kMT = 4;     // batch rows per WG
constexpr int kNT = 1024;  // threads per WG

static_assert(kK40 % 4 == 0 && kK41 % 4 == 0 && kK42 % 4 == 0, "ping-pong");
}  // namespace

// Mask element-width detection. mask0 row 0, columns 128..396 are the
// structurally all-true h-block (full = concat([m, ones(n_h,n_h)]) then .T).
__device__ __forceinline__ int detect_mask_mode(const void* m0) {
  const unsigned int* w = (const unsigned int*)m0;
  if (w[32] == 0x01010101u && w[33] == 0x01010101u &&
      w[34] == 0x01010101u && w[35] == 0x01010101u)
    return 0;  // uint8
  if (w[128] == 0x3F800000u && w[129] == 0x3F800000u && w[130] == 0x3F800000u)
    return 2;  // f32
  return 1;    // int32
}

__device__ __forceinline__ bool mask_at(const void* mk, int idx, int mode) {
  if (mode == 0) return ((const unsigned char*)mk)[idx] != 0;
  if (mode == 1) return ((const int*)mk)[idx] != 0;
  return ((const float*)mk)[idx] != 0.0f;
}

// ---------------------------------------------------------------------------
// Prep: packed masked/fused weights, layout W[cell][k4][col_padded][4].
// Pad cols/k-rows are exact zeros (so they contribute 0 to accumulators).
// ---------------------------------------------------------------------------
__global__ void prep_kernel(
    const void* __restrict__ m0_, const void* __restrict__ m1_,
    const void* __restrict__ m2_,
    const float* __restrict__ f1w0, const float* __restrict__ f2w0,
    const float* __restrict__ taw0, const float* __restrict__ tbw0,
    const float* __restrict__ f1w1, const float* __restrict__ f2w1,
    const float* __restrict__ taw1, const float* __restrict__ tbw1,
    const float* __restrict__ f1w2, const float* __restrict__ f2w2,
    const float* __restrict__ taw2, const float* __restrict__ tbw2,
    const float* __restrict__ f1b0, const float* __restrict__ f2b0,
    const float* __restrict__ tab0, const float* __restrict__ tbb0,
    const float* __restrict__ f1b1, const float* __restrict__ f2b1,
    const float* __restrict__ tab1, const float* __restrict__ tbb1,
    const float* __restrict__ f1b2, const float* __restrict__ f2b2,
    const float* __restrict__ tab2, const float* __restrict__ tbb2,
    float* __restrict__ ws) {
  int i = blockIdx.x * 256 + threadIdx.x;
  const int mode = detect_mask_mode(m0_);
  if (i < kQ) {
    int qi, NCp, ncols, cat, nh, baseq;
    const void* mk;
    const float *wf1, *wf2, *wta, *wtb;
    if (i < kQ0) {
      qi = i; NCp = kC0p; ncols = kC0r; cat = kCAT0; nh = kINTER; mk = m0_;
      wf1 = f1w0; wf2 = f2w0; wta = taw0; wtb = tbw0; baseq = 0;
    } else if (i < kQ0 + kQ1) {
      qi = i - kQ0; NCp = kC1p; ncols = kC1r; cat = kCAT1; nh = kCMD; mk = m1_;
      wf1 = f1w1; wf2 = f2w1; wta = taw1; wtb = tbw1; baseq = kQ0;
    } else {
      qi = i - kQ0 - kQ1; NCp = kC2p; ncols = kC2r; cat = kCAT2; nh = kMOTOR;
      mk = m2_;
      wf1 = f1w2; wf2 = f2w2; wta = taw2; wtb = tbw2; baseq = kQ0 + kQ1;
    }
    int k4 = qi / NCp;
    int j  = qi % NCp;
    float v[4] = {0.0f, 0.0f, 0.0f, 0.0f};
    if (j < ncols) {
#pragma unroll
      for (int kk = 0; kk < 4; ++kk) {
        int k = k4 * 4 + kk;
        float r = 0.0f;
        if (k < cat) {
          if (j < nh) {
            r = mask_at(mk, j * cat + k, mode) ? wf1[j * cat + k] : 0.0f;
          } else if (j < 2 * nh) {
            int jj = j - nh;
            r = mask_at(mk, jj * cat + k, mode) ? wf2[jj * cat + k] : 0.0f;
          } else {
            int jj = j - 2 * nh;
            r = wta[jj * cat + k] + wtb[jj * cat + k];
          }
        }
        v[kk] = r;
      }
    }
    ((float4*)ws)[baseq + qi] = make_float4(v[0], v[1], v[2], v[3]);
  } else if (i < kQ + kBCN) {
    int pos = i - kQ;
    int j = pos;
    int nh, ncols;
    const float *bf1, *bf2, *bta, *btb;
    if (j < kC0p) {
      nh = kINTER; ncols = kC0r;
      bf1 = f1b0; bf2 = f2b0; bta = tab0; btb = tbb0;
    } else if (j < kC0p + kC1p) {
      j -= kC0p; nh = kCMD; ncols = kC1r;
      bf1 = f1b1; bf2 = f2b1; bta = tab1; btb = tbb1;
    } else {
      j -= kC0p + kC1p; nh = kMOTOR; ncols = kC2r;
      bf1 = f1b2; bf2 = f2b2; bta = tab2; btb = tbb2;
    }
    float r = 0.0f;
    if (j < ncols) {
      if (j < nh) r = bf1[j];
      else if (j < 2 * nh) r = bf2[j - nh];
      else r = bta[j - 2 * nh] + btb[j - 2 * nh];
    }
    ws[kBCOff + pos] = r;
  }
}

// ---------------------------------------------------------------------------
// 8 FMAs per activation quad: one broadcast ds_read_b128 feeds TWO columns.
// ---------------------------------------------------------------------------
template <int AST>
__device__ __forceinline__ void fma_blk(const float4 wA, const float4 wB,
                                        const float* __restrict__ ak,
                                        float (&aA)[kMT], float (&aB)[kMT]) {
#pragma unroll
  for (int r = 0; r < kMT; ++r) {
    float4 av = *(const float4*)(ak + r * AST);
    aA[r] = fmaf(wA.x, av.x, aA[r]);
    aA[r] = fmaf(wA.y, av.y, aA[r]);
    aA[r] = fmaf(wA.z, av.z, aA[r]);
    aA[r] = fmaf(wA.w, av.w, aA[r]);
    aB[r] = fmaf(wB.x, av.x, aB[r]);
    aB[r] = fmaf(wB.y, av.y, aB[r]);
    aB[r] = fmaf(wB.z, av.z, aB[r]);
    aB[r] = fmaf(wB.w, av.w, aB[r]);
  }
}

// Two columns (jA, jB) x kMT rows. Ping-pong register sets w*/v* hold 4
// weight rows; prefetch of rows k4+4..k4+7 overlaps FMAs on k4..k4+3.
// Bias folded into accumulator init. Per-column math identical to R4.
template <int NK4, int NCOLS, int AST, int PST>
__device__ __forceinline__ void mv2(const float4* __restrict__ wp,
                                    const float* __restrict__ a,
                                    float* __restrict__ pc,
                                    const float* __restrict__ bias,
                                    int jA, int jB) {
  float aA[kMT], aB[kMT];
  const float bA = bias[jA], bB = bias[jB];
#pragma unroll
  for (int r = 0; r < kMT; ++r) { aA[r] = bA; aB[r] = bB; }
  const float4* pA = wp + jA;
  const float4* pB = wp + jB;
  float4 wA0 = pA[0 * NCOLS], wB0 = pB[0 * NCOLS];
  float4 wA1 = pA[1 * NCOLS], wB1 = pB[1 * NCOLS];
  float4 vA0 = pA[2 * NCOLS], vB0 = pB[2 * NCOLS];
  float4 vA1 = pA[3 * NCOLS], vB1 = pB[3 * NCOLS];
  const float* ak = a;
  int k4 = 0;
#pragma unroll 1
  for (; k4 + 8 <= NK4; k4 += 4) {
    fma_blk<AST>(wA0, wB0, ak, aA, aB);
    fma_blk<AST>(wA1, wB1, ak + 4, aA, aB);
    wA0 = pA[(k4 + 4) * NCOLS]; wB0 = pB[(k4 + 4) * NCOLS];
    wA1 = pA[(k4 + 5) * NCOLS]; wB1 = pB[(k4 + 5) * NCOLS];
    fma_blk<AST>(vA0, vB0, ak + 8, aA, aB);
    fma_blk<AST>(vA1, vB1, ak + 12, aA, aB);
    vA0 = pA[(k4 + 6) * NCOLS]; vB0 = pB[(k4 + 6) * NCOLS];
    vA1 = pA[(k4 + 7) * NCOLS]; vB1 = pB[(k4 + 7) * NCOLS];
    ak += 16;
  }
  // tail: last 4 k-rows already resident in the ping-pong sets
  fma_blk<AST>(wA0, wB0, ak, aA, aB);
  fma_blk<AST>(wA1, wB1, ak + 4, aA, aB);
  fma_blk<AST>(vA0, vB0, ak + 8, aA, aB);
  fma_blk<AST>(vA1, vB1, ak + 12, aA, aB);
#pragma unroll
  for (int r = 0; r < kMT; ++r) {
    pc[r * PST + jA] = aA[r];
    pc[r * PST + jB] = aB[r];
  }
}

__device__ __forceinline__ float cfc_combine(float p1, float p2, float pt) {
  float f1 = tanhf(p1);
  float f2 = tanhf(p2);
  float ti = 1.0f / (1.0f + expf(-pt));
  return f1 + ti * (f2 - f1);
}

// ---------------------------------------------------------------------------
// Pipelined persistent kernel. Phase p runs matvecs c0@t=p, c1@t=p-1,
// c2@t=p-2 plus the fc head for t=p-3, then all combines + x prefetch.
// Wave map (matvec section): 0-6 c0, 7-11 c1, 12-13 c2, 14-15 fc head.
// ---------------------------------------------------------------------------
__global__ __launch_bounds__(kNT) void ncp_main(
    const float* __restrict__ x, const float* __restrict__ hidden,
    const float* __restrict__ ws, const float* __restrict__ fcw,
    const float* __restrict__ fcb, float* __restrict__ out) {
  __shared__ __align__(16) float xc0[kMT][kS0];   // [x_t | h0 | pad]
  __shared__ __align__(16) float xc1[kMT][kS1];   // [n0  | h1]
  __shared__ __align__(16) float xc2[kMT][kS2];   // [n1  | h2 | pad]
  __shared__ __align__(16) float pa0[kMT][kC0p];  // pre-act cell0
  __shared__ __align__(16) float pa1[kMT][kC1p];  // pre-act cell1
  __shared__ __align__(16) float pa2[kMT][kC2p];  // pre-act cell2
  __shared__ float s_fcwT[64 * 64];               // fc_w transposed [m][o]
  __shared__ float s_bc[kBCN];
  __shared__ float s_fcb[64];

  const int tid = threadIdx.x;
  const int b0 = blockIdx.x * kMT;

  // zero xc (k-padding lanes must be 0.0f, not garbage: 0*NaN = NaN)
#pragma unroll
  for (int r = 0; r < kMT; ++r) {
    if (tid < kS0) xc0[r][tid] = 0.0f;
    if (tid < kS1) xc1[r][tid] = 0.0f;
    if (tid < kS2) xc2[r][tid] = 0.0f;
  }
  __syncthreads();
  // initial hidden state -> h slots
  for (int i = tid; i < kMT * kUNITS; i += kNT) {
    int r = i >> 9, u = i & 511;
    float v = hidden[(size_t)(b0 + r) * kUNITS + u];
    if (u < kINTER) xc0[r][kDIN + u] = v;
    else if (u < kINTER + kCMD) xc1[r][u] = v;  // layout offset == u
    else xc2[r][kCMD + (u - (kINTER + kCMD))] = v;
  }
  for (int i = tid; i < kBCN; i += kNT) s_bc[i] = ws[kBCOff + i];
  if (tid < 64) s_fcb[tid] = fcb[tid];
  for (int i = tid; i < 64 * 64; i += kNT) {
    int m = i >> 6, o = i & 63;
    s_fcwT[i] = fcw[o * 64 + m];
  }
  if (tid < 128) {  // stage x(0): 4 rows x 128 floats = 128 float4
    int r = tid >> 5, d4 = tid & 31;
    *(float4*)&xc0[r][d4 * 4] =
        *(const float4*)&x[(size_t)(b0 + r) * (kT * kDIN) + d4 * 4];
  }
  __syncthreads();

  const float4* wp0 = (const float4*)ws;
  const float4* wp1 = wp0 + kQ0;
  const float4* wp2 = wp1 + kQ1;

  for (int p = 0; p < kT + 3; ++p) {
    // ================= matvec + fc section =================
    if (tid < 448) {
      if (p < kT && tid < kP0)
        mv2<kK40, kC0p, kS0, kC0p>(wp0, &xc0[0][0], &pa0[0][0], s_bc,
                                   tid, tid + kP0);
    } else if (tid < 768) {
      const int pi = tid - 448;
      if (p >= 1 && p <= kT && pi < kP1)
        mv2<kK41, kC1p, kS1, kC1p>(wp1, &xc1[0][0], &pa1[0][0], s_bc + kC0p,
                                   pi, pi + kP1);
    } else if (tid < 896) {
      const int pi = tid - 768;
      if (p >= 2 && p <= kT + 1 && pi < kP2)
        mv2<kK42, kC2p, kS2, kC2p>(wp2, &xc2[0][0], &pa2[0][0],
                                   s_bc + kC0p + kC1p, pi, pi + kP2);
    } else if (p >= 3) {
      // fc head for t = p-3: reads n2(t) left in xc2 h-slot by comb2@p-1.
      const int i2 = tid - 896;        // 0..127
      const int o = i2 & 63;
      const int rb = (i2 >> 6) << 1;   // 0 or 2 (two rows per thread)
      const int t_fc = p - 3;
      float a0 = s_fcb[o], a1 = s_fcb[o];
      for (int m = 0; m < kMOTOR; ++m) {
        float w = s_fcwT[m * 64 + o];
        a0 = fmaf(xc2[rb][kCMD + m], w, a0);
        a1 = fmaf(xc2[rb + 1][kCMD + m], w, a1);
      }
      size_t base = (size_t)(b0 + rb) * (kT * kOUT) + (size_t)t_fc * kOUT + o;
      out[base] = a0;
      out[base + (size_t)kT * kOUT] = a1;
    }
    __syncthreads();
    // ================= combine + stage section =================
    if (tid < kINTER) {
      if (p < kT) {
#pragma unroll
        for (int r = 0; r < kMT; ++r) {
          float v = cfc_combine(pa0[r][tid], pa0[r][tid + kINTER],
                                pa0[r][tid + 2 * kINTER]);
          xc1[r][tid] = v;          // input to c1 (next phase)
          xc0[r][kDIN + tid] = v;   // h0 for c0@p+1
        }
      }
    } else if (tid >= 448 && tid < 448 + kCMD) {
      if (p >= 1 && p <= kT) {
        const int j = tid - 448;
#pragma unroll
        for (int r = 0; r < kMT; ++r) {
          float v = cfc_combine(pa1[r][j], pa1[r][j + kCMD],
                                pa1[r][j + 2 * kCMD]);
          xc2[r][j] = v;            // input to c2 (next phase)
          xc1[r][kINTER + j] = v;   // h1
        }
      }
    } else if (tid >= 768 && tid < 768 + kMOTOR) {
      if (p >= 2 && p <= kT + 1) {
        const int j = tid - 768;
#pragma unroll
        for (int r = 0; r < kMT; ++r) {
          float v = cfc_combine(pa2[r][j], pa2[r][j + kMOTOR],
                                pa2[r][j + 2 * kMOTOR]);
          xc2[r][kCMD + j] = v;     // h2 == n2(t) -> fc head @p+1
        }
      }
    } else if (tid >= 896) {
      if (p + 1 < kT) {  // prefetch x(p+1) for next phase's c0
        const int i2 = tid - 896;
        const int r = i2 >> 5, d4 = i2 & 31;
        *(float4*)&xc0[r][d4 * 4] =
            *(const float4*)&x[(size_t)(b0 + r) * (kT * kDIN) +
                               (size_t)(p + 1) * kDIN + d4 * 4];
      }
    }
    __syncthreads();
  }

  // final hidden state: h0(255)/h1(255)/h2(255) are in the h slots
  const size_t hnoff = (size_t)kBatch * kT * kOUT;
  for (int i = tid; i < kMT * kUNITS; i += kNT) {
    int r = i >> 9, u = i & 511;
    float v;
    if (u < kINTER) v = xc0[r][kDIN + u];
    else if (u < kINTER + kCMD) v = xc1[r][u];
    else v = xc2[r][kCMD + (u - (kINTER + kCMD))];
    out[hnoff + (size_t)(b0 + r) * kUNITS + u] = v;
  }
}

// ---------------------------------------------------------------------------
extern "C" void kernel_launch(void* const* d_in, const int* in_sizes, int n_in,
                              void* d_out, int out_size, void* d_ws, size_t ws_size,
                              hipStream_t stream) {
  (void)in_sizes; (void)n_in; (void)out_size; (void)ws_size;
  const float* x = (const float*)d_in[0];
  const float* hidden = (const float*)d_in[1];
  const void* m0 = d_in[2];
  const void* m1 = d_in[3];
  const void* m2 = d_in[4];
  const float* f1w0 = (const float*)d_in[5];
  const float* f1b0 = (const float*)d_in[6];
  const float* f2w0 = (const float*)d_in[7];
  const float* f2b0 = (const float*)d_in[8];
  const float* taw0 = (const float*)d_in[9];
  const float* tab0 = (const float*)d_in[10];
  const float* tbw0 = (const float*)d_in[11];
  const float* tbb0 = (const float*)d_in[12];
  const float* f1w1 = (const float*)d_in[13];
  const float* f1b1 = (const float*)d_in[14];
  const float* f2w1 = (const float*)d_in[15];
  const float* f2b1 = (const float*)d_in[16];
  const float* taw1 = (const float*)d_in[17];
  const float* tab1 = (const float*)d_in[18];
  const float* tbw1 = (const float*)d_in[19];
  const float* tbb1 = (const float*)d_in[20];
  const float* f1w2 = (const float*)d_in[21];
  const float* f1b2 = (const float*)d_in[22];
  const float* f2w2 = (const float*)d_in[23];
  const float* f2b2 = (const float*)d_in[24];
  const float* taw2 = (const float*)d_in[25];
  const float* tab2 = (const float*)d_in[26];
  const float* tbw2 = (const float*)d_in[27];
  const float* tbb2 = (const float*)d_in[28];
  const float* fcw = (const float*)d_in[29];
  const float* fcb = (const float*)d_in[30];
  float* ws = (float*)d_ws;
  float* out = (float*)d_out;

  const int prep_items = kQ + kBCN;  // 154882
  prep_kernel<<<(prep_items + 255) / 256, 256, 0, stream>>>(
      m0, m1, m2,
      f1w0, f2w0, taw0, tbw0,
      f1w1, f2w1, taw1, tbw1,
      f1w2, f2w2, taw2, tbw2,
      f1b0, f2b0, tab0, tbb0,
      f1b1, f2b1, tab1, tbb1,
      f1b2, f2b2, tab2, tbb2,
      ws);

  ncp_main<<<kBatch / kMT, kNT, 0, stream>>>(x, hidden, ws, fcw, fcb, out);
}